// Round 7
// baseline (151.603 us; speedup 1.0000x reference)
//
#include <hip/hip_runtime.h>

// Problem constants (from reference): B=8, E=512, L=4096, D=256, all fp32.
#define B_N 8
#define E_N 512
#define L_N 4096
#define D_N 256

#define SPLITK 8
#define KC_LEN (L_N / SPLITK)   // 512
#define BK 64
#define KC_ITERS (KC_LEN / BK)  // 8

#define ET 64                   // E tile  (R7: halved -> 1024 blocks = 4/CU)
#define DT 128                  // D tile
#define NTHREADS 512

#define SLICE_ELEMS (B_N * E_N * D_N)           // 1M floats = 4 MB per split slice

typedef __attribute__((ext_vector_type(8))) short short8;   // 8 bf16 (MFMA A/B frag)
typedef __attribute__((ext_vector_type(4))) float f32x4;    // MFMA acc / global float4
typedef __attribute__((ext_vector_type(2))) unsigned int uint2v; // 2x packed bf16 pair

// Packed fp32x2 -> bf16x2 (RNE) in ONE VALU op (R4: VALUBusy 14% -> 4.4%).
__device__ __forceinline__ unsigned cvt_pk_bf16(float lo, float hi) {
    unsigned r;
    asm("v_cvt_pk_bf16_f32 %0, %1, %2" : "=v"(r) : "v"(lo), "v"(hi));
    return r;
}

// LDS tile: [row][64 k] bf16, 128 B per row, NO pad. 16B-chunk XOR swizzle
// (verified R2: SQ_LDS_BANK_CONFLICT 5.2M -> 0). k multiple of 4 at call sites.
__device__ __forceinline__ int swz(int row, int k) {
    return row * 64 + ((((k >> 3) ^ (row & 7)) << 3) | (k & 7));
}

// ---------------- Stage 1: split-K partial GEMM, NO atomics ----------------
// R6 lesson: 512 blocks / 256 CU = 2 blocks/CU NO MATTER the LDS/VGPR headroom
// (Occupancy stuck ~30%, dur ~45us across R3-R6). R7 halves the tile along E
// -> 1024 blocks -> 4 independent barrier groups per CU to fill each other's
// barrier-drain bubbles. Per-block: LDS 24KB (4x24=96<160), 8 waves (4x8=32),
// staging 24 VGPR -> no spill at the (512,4) cap.
// FAILED, do not repeat: (512,8) VGPR crush -> spill (R5, WRITE 285MB);
// distance-2 reg pipeline -> spill (R4, WRITE 104MB).
__global__ __launch_bounds__(NTHREADS, 4)
void mp_gemm(const float* __restrict__ doc,   // [B, L, D]
             const float* __restrict__ map,   // [B, E, L]
             float* __restrict__ ws)          // [SPLITK, B, E, D] partials
{
    // SINGLE-buffered swizzled tiles: 24 KiB total.
    __shared__ unsigned short As[ET * 64];   // As[m][k] : map tile, K-contig (8 KB)
    __shared__ unsigned short Bs[DT * 64];   // Bs[n][k] : doc tile transposed (16 KB)

    // XCD-chunked swizzle: each XCD owns 128 consecutive w = 8 complete (b,kc)
    // groups; a group's 16 tiles share doc/map panels in that XCD's L2.
    const int p    = (int)blockIdx.x;            // 0..1023
    const int w    = ((p & 7) << 7) | (p >> 3);
    const int tile = w & 15;       // et*2 + dt
    const int grp  = w >> 4;       // 0..63
    const int b    = grp & 7;
    const int kc   = grp >> 3;     // 0..7

    const int e0  = (tile >> 1) * ET;   // 8 E tiles
    const int d0  = (tile & 1) * DT;    // 2 D tiles
    const int kc0 = kc * KC_LEN;

    const float* docB = doc + (size_t)b * L_N * D_N;
    const float* mapB = map + (size_t)b * E_N * L_N;
    float* wsB = ws + (size_t)kc * SLICE_ELEMS + (size_t)b * E_N * D_N;

    const int tid  = threadIdx.x;
    const int lane = tid & 63;
    const int wave = tid >> 6;     // 0..7

    // ---- staging assignments ----
    // A tile 64(m) x 64(k) fp32: thread t -> rows (t>>4)+32r (r=0..1), col4 = t&15
    //   per instruction: 16 lanes x 16B = 256B contiguous per row
    const int aRow0 = tid >> 4;    // 0..31
    const int aCol4 = tid & 15;
    // B tile 64(k) x 128(n) fp32: one 4(k)x4(n) micro-block per thread
    // (byte-identical staging pattern to R6: f32x4 reads, 0-conflict LDS writes)
    const int kb = tid & 15;       // k block: varies across lanes (LDS chunk spread)
    const int nb = tid >> 4;       // n block (0..31)

    f32x4 ar[2], br[4];            // 24 staging VGPRs

    #define LOAD_SET(K0)                                                                   \
        do {                                                                               \
            _Pragma("unroll")                                                              \
            for (int r = 0; r < 2; ++r)                                                    \
                ar[r] = *(const f32x4*)(mapB + (size_t)(e0 + aRow0 + r * 32) * L_N +       \
                                        (K0) + aCol4 * 4);                                 \
            _Pragma("unroll")                                                              \
            for (int i = 0; i < 4; ++i)                                                    \
                br[i] = *(const f32x4*)(docB + (size_t)((K0) + kb * 4 + i) * D_N +         \
                                        d0 + nb * 4);                                      \
        } while (0)

    // ---- compute setup: 8 waves in 2(m) x 4(n) grid; each wave 32x32 output ----
    const int wm = wave >> 2;      // 0..1 : 32-row block
    const int wn = wave & 3;       // 0..3 : 32-col block
    const int fm = lane & 15;
    const int q  = lane >> 4;

    f32x4 acc[2][2] = {};

    LOAD_SET(kc0);                 // prologue: tile-0 loads in flight

    for (int it = 0; it < KC_ITERS; ++it) {
        // Convert + stage to LDS. Compiler inserts the counted vmcnt wait for
        // ar/br right here (this is the only consumer).
        #pragma unroll
        for (int r = 0; r < 2; ++r) {
            uint2v wv;
            wv[0] = cvt_pk_bf16(ar[r][0], ar[r][1]);
            wv[1] = cvt_pk_bf16(ar[r][2], ar[r][3]);
            *(uint2v*)&As[swz(aRow0 + r * 32, aCol4 * 4)] = wv;
        }
        #pragma unroll
        for (int j = 0; j < 4; ++j) {
            uint2v wv;
            wv[0] = cvt_pk_bf16(br[0][j], br[1][j]);
            wv[1] = cvt_pk_bf16(br[2][j], br[3][j]);
            *(uint2v*)&Bs[swz(nb * 4 + j, kb * 4)] = wv;
        }

        // Reissue the (now-consumed) set for it+1.
        if (it + 1 < KC_ITERS) LOAD_SET(kc0 + (it + 1) * BK);
        __builtin_amdgcn_sched_barrier(0);

        // Barrier 1: writes visible before reads. LDS-only wait -- globals
        // stay in flight across it.
        asm volatile("s_waitcnt lgkmcnt(0)" ::: "memory");
        __builtin_amdgcn_s_barrier();
        __builtin_amdgcn_sched_barrier(0);

        // Frag reads + MFMA on the staged 64x128x64 tile (2 K-steps of 32).
        // setprio: with 4 phase-desynced blocks/CU, favor the MFMA-issuing wave.
        __builtin_amdgcn_s_setprio(1);
        #pragma unroll
        for (int kk = 0; kk < 2; ++kk) {
            short8 af[2], bf[2];
            #pragma unroll
            for (int mi = 0; mi < 2; ++mi) {
                const int m = wm * 32 + mi * 16 + fm;
                af[mi] = *(const short8*)&As[swz(m, kk * 32 + q * 8)];
            }
            #pragma unroll
            for (int ni = 0; ni < 2; ++ni) {
                const int n = wn * 32 + ni * 16 + fm;
                bf[ni] = *(const short8*)&Bs[swz(n, kk * 32 + q * 8)];
            }
            #pragma unroll
            for (int mi = 0; mi < 2; ++mi)
                #pragma unroll
                for (int ni = 0; ni < 2; ++ni)
                    acc[mi][ni] = __builtin_amdgcn_mfma_f32_16x16x32_bf16(
                        af[mi], bf[ni], acc[mi][ni], 0, 0, 0);
        }
        __builtin_amdgcn_s_setprio(0);

        // Barrier 2 (single-buffer): reads done in all waves before anyone
        // overwrites the buffer. sched_barrier keeps next-iter ds_writes from
        // hoisting above (raw s_barrier is not a compiler memory fence).
        __builtin_amdgcn_s_barrier();
        __builtin_amdgcn_sched_barrier(0);
    }
    #undef LOAD_SET

    // ---- epilogue: plain stores of the partial tile to this block's private
    // workspace slice. C/D layout: col = lane&15, row = (lane>>4)*4 + i.
    #pragma unroll
    for (int mi = 0; mi < 2; ++mi) {
        const int rLoc = wm * 32 + mi * 16 + q * 4;
        #pragma unroll
        for (int ni = 0; ni < 2; ++ni) {
            const int c = d0 + wn * 32 + ni * 16 + fm;
            #pragma unroll
            for (int i = 0; i < 4; ++i) {
                const int rr = rLoc + i;
                wsB[(size_t)(e0 + rr) * D_N + c] = acc[mi][ni][i];
            }
        }
    }
}

// ---------------- Stage 2: reduce slices + scale by 1/len ----------------
__global__ __launch_bounds__(256)
void mp_reduce(const float* __restrict__ ws,    // [SPLITK, B*E*D]
               const float* __restrict__ lens,  // [B, E]
               float* __restrict__ out)         // [B*E*D]
{
    const int t = (int)blockIdx.x * 256 + (int)threadIdx.x;  // float4 index
    const size_t off = (size_t)t * 4;
    const int be = t >> 6;            // D/4 = 64 float4 per (b,e) row

    f32x4 s = {};
    #pragma unroll
    for (int k = 0; k < SPLITK; ++k) {
        const f32x4 v = *(const f32x4*)(ws + (size_t)k * SLICE_ELEMS + off);
        s += v;
    }
    const float il = 1.0f / lens[be];
    s *= il;
    *(f32x4*)(out + off) = s;
}

extern "C" void kernel_launch(void* const* d_in, const int* in_sizes, int n_in,
                              void* d_out, int out_size, void* d_ws, size_t ws_size,
                              hipStream_t stream) {
    const float* doc  = (const float*)d_in[0];  // doc_state [B,L,D]
    const float* map  = (const float*)d_in[1];  // entity_mapping [B,E,L]
    const float* lens = (const float*)d_in[2];  // entity_lens [B,E]
    float* out = (float*)d_out;                 // [B,E,D] fp32
    float* ws  = (float*)d_ws;                  // needs 32 MB (SPLITK slices)

    // No memset needed: stage 1 fully writes every ws element, stage 2 fully
    // overwrites out.
    dim3 grid1(SPLITK * 16 * B_N);  // 1024 blocks: 16 tiles x 8 b x 8 kc -> 4/CU
    mp_gemm<<<grid1, NTHREADS, 0, stream>>>(doc, map, ws);

    dim3 grid2(SLICE_ELEMS / 4 / 256);  // 1024 blocks
    mp_reduce<<<grid2, 256, 0, stream>>>(ws, lens, out);
}